// Round 5
// baseline (265.723 us; speedup 1.0000x reference)
//
#include <hip/hip_runtime.h>
#include <hip/hip_bf16.h>
#include <math.h>

// Problem constants (fixed by the reference file)
#define T_TOK 2048
#define H_DIM 1024
#define I_DIM 2048
#define E_NUM 8
#define TOPK  2
#define P_MAX (T_TOK * TOPK)   // 4096 (token, k) pairs
#define MAX_SLOTS 40           // sum_e ceil(M_e/128) <= 32 + 7 = 39

typedef __bf16 bf16_t;
typedef __attribute__((ext_vector_type(8))) __bf16 bf16x8;
typedef __attribute__((ext_vector_type(4))) float  f32x4;

// global_load_lds: per-lane GLOBAL address, wave-uniform LDS base; lane n
// writes lds_base + n*16 bytes (m104/m108). 16B width (m97: +67%).
#define GLOAD_LDS16(gptr, lptr)                                                   \
    __builtin_amdgcn_global_load_lds(                                             \
        (const __attribute__((address_space(1))) void*)(gptr),                    \
        (__attribute__((address_space(3))) void*)(lptr), 16, 0, 0)

__device__ inline f32x4 zero4() {
    f32x4 z; z[0] = 0.f; z[1] = 0.f; z[2] = 0.f; z[3] = 0.f; return z;
}

__device__ inline bf16x8 cvt8(f32x4 a, f32x4 b) {
    bf16x8 o;
    o[0] = (bf16_t)a[0]; o[1] = (bf16_t)a[1]; o[2] = (bf16_t)a[2]; o[3] = (bf16_t)a[3];
    o[4] = (bf16_t)b[0]; o[5] = (bf16_t)b[1]; o[6] = (bf16_t)b[2]; o[7] = (bf16_t)b[3];
    return o;
}

// ---------------------------------------------------------------- init
__global__ void init_kernel(int* counts, int* cursor) {
    int i = threadIdx.x;
    if (i < E_NUM) { counts[i] = 0; cursor[i] = 0; }
}

// ---------------------------------------------------------------- router
__global__ void router_kernel(const float* __restrict__ gating,
                              int* __restrict__ expert_id,
                              float* __restrict__ wt,
                              int* __restrict__ counts) {
    int t = blockIdx.x * blockDim.x + threadIdx.x;
    if (t >= T_TOK) return;
    float l[E_NUM];
    float m = -1e30f;
    #pragma unroll
    for (int e = 0; e < E_NUM; e++) { l[e] = gating[t * E_NUM + e]; m = fmaxf(m, l[e]); }
    float p[E_NUM];
    #pragma unroll
    for (int e = 0; e < E_NUM; e++) p[e] = __expf(l[e] - m);
    int i0 = 0; float p0 = p[0];
    #pragma unroll
    for (int e = 1; e < E_NUM; e++) if (p[e] > p0) { p0 = p[e]; i0 = e; }
    int i1 = -1; float p1 = -1.f;
    #pragma unroll
    for (int e = 0; e < E_NUM; e++) if (e != i0 && p[e] > p1) { p1 = p[e]; i1 = e; }
    float inv = 1.f / (p0 + p1);
    expert_id[t * 2 + 0] = i0; wt[t * 2 + 0] = p0 * inv;
    expert_id[t * 2 + 1] = i1; wt[t * 2 + 1] = p1 * inv;
    atomicAdd(&counts[i0], 1);
    atomicAdd(&counts[i1], 1);
}

// ---------------------------------------------------------------- scan + tile map
__global__ void scan_kernel(const int* __restrict__ counts,
                            int* __restrict__ offsets,
                            int* __restrict__ tile_e, int* __restrict__ tile_m0,
                            int* __restrict__ n_slots) {
    if (threadIdx.x != 0 || blockIdx.x != 0) return;
    int off = 0;
    for (int e = 0; e < E_NUM; e++) { offsets[e] = off; off += counts[e]; }
    offsets[E_NUM] = off;
    int s = 0;
    for (int e = 0; e < E_NUM; e++)
        for (int m0 = offsets[e]; m0 < offsets[e + 1]; m0 += 128) {
            tile_e[s] = e; tile_m0[s] = m0; s++;
        }
    *n_slots = s;
}

// ---------------------------------------------------------------- scatter
__global__ void scatter_kernel(const int* __restrict__ expert_id,
                               const float* __restrict__ wt,
                               const int* __restrict__ offsets,
                               int* __restrict__ cursor,
                               int* __restrict__ pair_token,
                               int* __restrict__ pair_dst,
                               float* __restrict__ pair_wt) {
    int t = blockIdx.x * blockDim.x + threadIdx.x;
    if (t >= T_TOK) return;
    #pragma unroll
    for (int k = 0; k < TOPK; k++) {
        int e = expert_id[t * 2 + k];
        int p = offsets[e] + atomicAdd(&cursor[e], 1);
        pair_token[p] = t;
        pair_dst[p]   = t * 2 + k;
        pair_wt[p]    = wt[t * 2 + k];
    }
}

// ---------------------------------------------------------------- f32 -> bf16 convert
// Branch-free, 64B loads / 32B stores per thread-iteration, nontemporal f32
// reads (streamed once, never reused -> keep bf16 output resident in L3).
__global__ void convert_kernel(const float* __restrict__ src,
                               bf16_t* __restrict__ dst,
                               size_t n16) {   // # of 16-elt granules
    size_t stride = (size_t)gridDim.x * blockDim.x;
    for (size_t g = (size_t)blockIdx.x * blockDim.x + threadIdx.x; g < n16; g += stride) {
        size_t i = g * 16;
        f32x4 a0 = __builtin_nontemporal_load((const f32x4*)(src + i));
        f32x4 a1 = __builtin_nontemporal_load((const f32x4*)(src + i + 4));
        f32x4 a2 = __builtin_nontemporal_load((const f32x4*)(src + i + 8));
        f32x4 a3 = __builtin_nontemporal_load((const f32x4*)(src + i + 12));
        *(bf16x8*)(dst + i)     = cvt8(a0, a1);
        *(bf16x8*)(dst + i + 8) = cvt8(a2, a3);
    }
}

// ---------------------------------------------------------------- GEMM1 + SwiGLU
// m97-clone: out-tile 128 pair-rows x 64 act-cols; B-tile = 128 w1 rows
// (rows 0-63 = gate strip c0.., rows 64-127 = up strip I+c0..). BK=64.
// LDS linear 2x16KB, staged via global_load_lds(16). 4 waves 2x2.
// Grid flattened + chunked XCD swizzle: XCD x owns blocks [x*160,(x+1)*160)
// in slot-major order -> each slot's A tile (256KB bf16) is read by 32
// consecutive same-XCD blocks = L2-resident reuse.
__global__ __launch_bounds__(256)
void gemm1_kernel(const bf16_t* __restrict__ hbf,
                  const bf16_t* __restrict__ w1bf,
                  const int* __restrict__ pair_token,
                  const int* __restrict__ offsets,
                  const int* __restrict__ tile_e,
                  const int* __restrict__ tile_m0,
                  const int* __restrict__ n_slots,
                  bf16_t* __restrict__ act) {
    int P = blockIdx.x;                    // 1280 = 8 XCD-chunks x 160
    int L = (P & 7) * 160 + (P >> 3);      // bijective chunked swizzle
    int slot = L >> 5;
    int c0   = (L & 31) << 6;              // act cols [c0, c0+64)
    if (slot >= *n_slots) return;
    int e    = tile_e[slot];
    int m0   = tile_m0[slot];
    int mend = offsets[e + 1];
    const bf16_t* w1e = w1bf + (size_t)e * (2 * I_DIM) * H_DIM;

    __shared__ __align__(16) bf16_t sA[128][64];  // 16 KB
    __shared__ __align__(16) bf16_t sB[128][64];  // 16 KB

    int tid = threadIdx.x;
    int lane = tid & 63, w = tid >> 6;
    int wm = w >> 1, wn = w & 1;
    int l15 = lane & 15, lg = lane >> 4;
    int lr = lane >> 3, lk = (lane & 7) * 8;

    // per-thread global staging addresses (k0 added in loop)
    const bf16_t* gA[4];
    const bf16_t* gB[4];
    #pragma unroll
    for (int i = 0; i < 4; i++) {
        int row = w * 32 + i * 8 + lr;
        int pr  = m0 + row;
        int tok = (pr < mend) ? pair_token[pr] : 0;   // safe dummy row
        gA[i] = hbf + (size_t)tok * H_DIM + lk;
        int w1row = (row < 64) ? (c0 + row) : (I_DIM + c0 + (row - 64));
        gB[i] = w1e + (size_t)w1row * H_DIM + lk;
    }

    f32x4 acc[4][4];  // [i][0..1]=gate, [i][2..3]=up
    #pragma unroll
    for (int i = 0; i < 4; i++)
        #pragma unroll
        for (int j = 0; j < 4; j++) acc[i][j] = zero4();

    for (int k0 = 0; k0 < H_DIM; k0 += 64) {
        __syncthreads();   // previous compute done; LDS reusable
        #pragma unroll
        for (int i = 0; i < 4; i++) GLOAD_LDS16(gA[i] + k0, &sA[w * 32 + i * 8][0]);
        #pragma unroll
        for (int i = 0; i < 4; i++) GLOAD_LDS16(gB[i] + k0, &sB[w * 32 + i * 8][0]);
        __syncthreads();   // vmcnt(0) drain -> tile ready

        #pragma unroll
        for (int kh = 0; kh < 2; kh++) {
            int koff = kh * 32 + lg * 8;
            bf16x8 a[4], bg[2], bu[2];
            #pragma unroll
            for (int i = 0; i < 4; i++)
                a[i] = *(const bf16x8*)&sA[wm * 64 + i * 16 + l15][koff];
            #pragma unroll
            for (int j = 0; j < 2; j++) {
                bg[j] = *(const bf16x8*)&sB[wn * 32 + j * 16 + l15][koff];
                bu[j] = *(const bf16x8*)&sB[64 + wn * 32 + j * 16 + l15][koff];
            }
            #pragma unroll
            for (int i = 0; i < 4; i++)
                #pragma unroll
                for (int j = 0; j < 2; j++) {
                    acc[i][j]     = __builtin_amdgcn_mfma_f32_16x16x32_bf16(a[i], bg[j], acc[i][j], 0, 0, 0);
                    acc[i][2 + j] = __builtin_amdgcn_mfma_f32_16x16x32_bf16(a[i], bu[j], acc[i][2 + j], 0, 0, 0);
                }
        }
    }

    // epilogue: act = silu(gate) * up
    #pragma unroll
    for (int i = 0; i < 4; i++) {
        #pragma unroll
        for (int rr = 0; rr < 4; rr++) {
            int m = m0 + wm * 64 + i * 16 + lg * 4 + rr;
            if (m < mend) {
                #pragma unroll
                for (int j = 0; j < 2; j++) {
                    float gv = acc[i][j][rr];
                    float uv = acc[i][2 + j][rr];
                    float sv = gv / (1.f + __expf(-gv));
                    act[(size_t)m * I_DIM + c0 + wn * 32 + j * 16 + l15] = (bf16_t)(sv * uv);
                }
            }
        }
    }
}

// ---------------------------------------------------------------- GEMM2 (+ scale, k-split)
// out-tile 128 rows x 128 cols, BK=64, K split in 2 slices of 1024 (kz).
// Slice kz writes ybuf + kz*P_MAX*H; combine sums both (deterministic).
// Grid flattened 640 = 8 chunks x 80, slot-major within chunk (A L2 reuse).
__global__ __launch_bounds__(256)
void gemm2_kernel(const bf16_t* __restrict__ act,
                  const bf16_t* __restrict__ w2bf,
                  const int* __restrict__ offsets,
                  const int* __restrict__ tile_e,
                  const int* __restrict__ tile_m0,
                  const int* __restrict__ n_slots,
                  const int* __restrict__ pair_dst,
                  const float* __restrict__ pair_wt,
                  float* __restrict__ ybuf) {
    int P = blockIdx.x;                    // 640 = 8 x 80
    int L = (P & 7) * 80 + (P >> 3);
    int slot = L >> 4;
    int kz   = (L >> 3) & 1;
    int n0   = (L & 7) << 7;
    if (slot >= *n_slots) return;
    int e    = tile_e[slot];
    int m0   = tile_m0[slot];
    int mend = offsets[e + 1];
    int kb   = kz * (I_DIM / 2);   // k-slice base
    const bf16_t* w2e = w2bf + (size_t)e * H_DIM * I_DIM;

    __shared__ __align__(16) bf16_t sA[128][64];
    __shared__ __align__(16) bf16_t sB[128][64];

    int tid = threadIdx.x;
    int lane = tid & 63, w = tid >> 6;
    int wm = w >> 1, wn = w & 1;
    int l15 = lane & 15, lg = lane >> 4;
    int lr = lane >> 3, lk = (lane & 7) * 8;

    const bf16_t* gA[4];
    const bf16_t* gB[4];
    #pragma unroll
    for (int i = 0; i < 4; i++) {
        int row = w * 32 + i * 8 + lr;
        // rows >= mend read neighbor data (in-arena, masked at epilogue)
        gA[i] = act + (size_t)(m0 + row) * I_DIM + kb + lk;
        gB[i] = w2e + (size_t)(n0 + row) * I_DIM + kb + lk;
    }

    f32x4 acc[4][4];
    #pragma unroll
    for (int i = 0; i < 4; i++)
        #pragma unroll
        for (int j = 0; j < 4; j++) acc[i][j] = zero4();

    for (int k0 = 0; k0 < I_DIM / 2; k0 += 64) {
        __syncthreads();
        #pragma unroll
        for (int i = 0; i < 4; i++) GLOAD_LDS16(gA[i] + k0, &sA[w * 32 + i * 8][0]);
        #pragma unroll
        for (int i = 0; i < 4; i++) GLOAD_LDS16(gB[i] + k0, &sB[w * 32 + i * 8][0]);
        __syncthreads();

        #pragma unroll
        for (int kh = 0; kh < 2; kh++) {
            int koff = kh * 32 + lg * 8;
            bf16x8 a[4], b[4];
            #pragma unroll
            for (int i = 0; i < 4; i++)
                a[i] = *(const bf16x8*)&sA[wm * 64 + i * 16 + l15][koff];
            #pragma unroll
            for (int j = 0; j < 4; j++)
                b[j] = *(const bf16x8*)&sB[wn * 64 + j * 16 + l15][koff];
            #pragma unroll
            for (int i = 0; i < 4; i++)
                #pragma unroll
                for (int j = 0; j < 4; j++)
                    acc[i][j] = __builtin_amdgcn_mfma_f32_16x16x32_bf16(a[i], b[j], acc[i][j], 0, 0, 0);
        }
    }

    float* ybufz = ybuf + (size_t)kz * P_MAX * H_DIM;
    #pragma unroll
    for (int i = 0; i < 4; i++) {
        #pragma unroll
        for (int rr = 0; rr < 4; rr++) {
            int m = m0 + wm * 64 + i * 16 + lg * 4 + rr;
            if (m < mend) {
                int   dst = pair_dst[m];
                float wv  = pair_wt[m];
                #pragma unroll
                for (int j = 0; j < 4; j++)
                    ybufz[(size_t)dst * H_DIM + n0 + wn * 64 + j * 16 + l15] = acc[i][j][rr] * wv;
            }
        }
    }
}

// ---------------------------------------------------------------- combine
__global__ void combine_kernel(const float* __restrict__ ybuf,
                               float* __restrict__ out) {
    int idx = blockIdx.x * 256 + threadIdx.x;   // one float4 each
    int t = idx >> 8;                           // 256 float4 per token row
    int h = idx & 255;
    const size_t SL = (size_t)P_MAX * H_DIM;
    const f32x4* y00 = (const f32x4*)(ybuf + (size_t)(t * 2)     * H_DIM) + h;
    const f32x4* y01 = (const f32x4*)(ybuf + (size_t)(t * 2 + 1) * H_DIM) + h;
    const f32x4* y10 = (const f32x4*)(ybuf + SL + (size_t)(t * 2)     * H_DIM) + h;
    const f32x4* y11 = (const f32x4*)(ybuf + SL + (size_t)(t * 2 + 1) * H_DIM) + h;
    f32x4 s = (*y00 + *y10) + (*y01 + *y11);
    ((f32x4*)out)[idx] = s;
}

// ---------------------------------------------------------------- launch
extern "C" void kernel_launch(void* const* d_in, const int* in_sizes, int n_in,
                              void* d_out, int out_size, void* d_ws, size_t ws_size,
                              hipStream_t stream) {
    const float* hidden = (const float*)d_in[0];
    const float* w1     = (const float*)d_in[1];
    const float* w2     = (const float*)d_in[2];
    const float* gating = (const float*)d_in[3];
    float* out = (float*)d_out;

    const size_t N0 = (size_t)T_TOK * H_DIM;             // hidden elems
    const size_t N1 = (size_t)E_NUM * 2 * I_DIM * H_DIM; // w1 elems
    const size_t N2 = (size_t)E_NUM * H_DIM * I_DIM;     // w2 elems

    char* ws = (char*)d_ws;
    size_t off = 0;
    auto alloc = [&](size_t bytes) -> void* {
        void* p = ws + off;
        off += (bytes + 255) & ~(size_t)255;
        return p;
    };
    // order matters: act must not be last (gemm2 A-staging over-reads <=516KB)
    float*  ybuf  = (float*)alloc((size_t)2 * P_MAX * H_DIM * sizeof(float));     // 33.6 MB (2 slices)
    bf16_t* act   = (bf16_t*)alloc((size_t)P_MAX * I_DIM * sizeof(bf16_t));       // 16.8 MB
    bf16_t* hbf   = (bf16_t*)alloc(N0 * sizeof(bf16_t));                          //  4.2 MB
    bf16_t* w1bf  = (bf16_t*)alloc(N1 * sizeof(bf16_t));                          // 67.1 MB
    bf16_t* w2bf  = (bf16_t*)alloc(N2 * sizeof(bf16_t));                          // 33.6 MB
    int*    expert_id  = (int*)alloc(P_MAX * sizeof(int));
    float*  wt         = (float*)alloc(P_MAX * sizeof(float));
    int*    pair_token = (int*)alloc(P_MAX * sizeof(int));
    int*    pair_dst   = (int*)alloc(P_MAX * sizeof(int));
    float*  pair_wt    = (float*)alloc(P_MAX * sizeof(float));
    int*    counts     = (int*)alloc(E_NUM * sizeof(int));
    int*    offsets    = (int*)alloc((E_NUM + 1) * sizeof(int));
    int*    cursor     = (int*)alloc(E_NUM * sizeof(int));
    int*    n_slots    = (int*)alloc(sizeof(int));
    int*    tile_e     = (int*)alloc(MAX_SLOTS * sizeof(int));
    int*    tile_m0    = (int*)alloc(MAX_SLOTS * sizeof(int));

    init_kernel<<<1, 64, 0, stream>>>(counts, cursor);
    router_kernel<<<(T_TOK + 255) / 256, 256, 0, stream>>>(gating, expert_id, wt, counts);
    scan_kernel<<<1, 1, 0, stream>>>(counts, offsets, tile_e, tile_m0, n_slots);
    scatter_kernel<<<(T_TOK + 255) / 256, 256, 0, stream>>>(expert_id, wt, offsets, cursor,
                                                            pair_token, pair_dst, pair_wt);
    convert_kernel<<<512,  256, 0, stream>>>(hidden, hbf,  N0 / 16);
    convert_kernel<<<2048, 256, 0, stream>>>(w1,     w1bf, N1 / 16);
    convert_kernel<<<2048, 256, 0, stream>>>(w2,     w2bf, N2 / 16);
    gemm1_kernel<<<dim3(MAX_SLOTS * 32), 256, 0, stream>>>(
        hbf, w1bf, pair_token, offsets, tile_e, tile_m0, n_slots, act);
    gemm2_kernel<<<dim3(MAX_SLOTS * 16), 256, 0, stream>>>(
        act, w2bf, offsets, tile_e, tile_m0, n_slots, pair_dst, pair_wt, ybuf);
    combine_kernel<<<(T_TOK * H_DIM / 4) / 256, 256, 0, stream>>>(ybuf, out);

    (void)in_sizes; (void)n_in; (void)out_size; (void)ws_size;
}